// Round 16
// baseline (1824.400 us; speedup 1.0000x reference)
//
#include <hip/hip_runtime.h>
#include <math.h>

// Problem constants
#define NB   2
#define SEQ  2048
#define NHD  16
#define HDD  64
#define HID  1024
#define TOPK 128

// Branch-free fp64 exp for |x| <= ~60 (here |x| <= 8). Cody-Waite + degree-12 Taylor (r14-verified).
__device__ __forceinline__ double fast_exp(double x) {
  double n = rint(x * 1.44269504088896340736);
  double r = fma(n, -6.93147180369123816490e-01, x);
  r = fma(n, -1.90821492927058770002e-10, r);
  double p = 2.08767569878680989792e-09;
  p = fma(p, r, 2.50521083854417187751e-08);
  p = fma(p, r, 2.75573192239858906526e-07);
  p = fma(p, r, 2.75573192239858882510e-06);
  p = fma(p, r, 2.48015873015873015873e-05);
  p = fma(p, r, 1.98412698412698412698e-04);
  p = fma(p, r, 1.38888888888888888889e-03);
  p = fma(p, r, 8.33333333333333333333e-03);
  p = fma(p, r, 4.16666666666666666667e-02);
  p = fma(p, r, 1.66666666666666666667e-01);
  p = fma(p, r, 5.00000000000000000000e-01);
  p = fma(p, r, 1.0);
  p = fma(p, r, 1.0);
  long long k = (long long)(int)n;
  double sc = __longlong_as_double((k + 1023LL) << 52);
  return p * sc;
}

// ---------------- K0a: vw = mean(sparse_W_V, axis=2), ow = mean(sparse_W_O, axis=1) (fp64) ----------
__global__ void k_prep_means(const float* __restrict__ sWV, const float* __restrict__ sWO,
                             double* __restrict__ vw, double* __restrict__ ow) {
  int t = threadIdx.x;
  for (int o = t; o < NHD * HDD; o += 256) {
    const float* p = sWV + (size_t)o * TOPK;
    double s = 0.0;
    for (int i = 0; i < TOPK; i++) s += (double)p[i];
    vw[o] = s * (1.0 / 128.0);
    int h = o >> 6, d = o & 63;
    const float* q = sWO + ((size_t)h * TOPK) * HDD + d;
    double s2 = 0.0;
    for (int i = 0; i < TOPK; i++) s2 += (double)q[(size_t)i * HDD];
    ow[o] = s2 * (1.0 / 128.0);
  }
}

// ---------------- K0b: WVP[(n*16+h), j] = sum_d W_V[n*64+d, j]*vw[h,d]  (fp64)
//                       G[(m*16+h), o]  = sum_d ow[h,d]*W_O[o, m*64+d]  (fp32) ----------------------
__global__ void k_prep_wvp_g(const float* __restrict__ W_V, const float* __restrict__ W_O,
                             const double* __restrict__ vw, const double* __restrict__ ow,
                             double* __restrict__ WVP, float* __restrict__ G) {
  int blk = blockIdx.x;
  int t = threadIdx.x;
  if (blk < 256) {
    int n = blk >> 4, h = blk & 15;
    for (int j = t; j < HID; j += 256) {
      double s = 0.0;
      for (int d = 0; d < 64; d++)
        s += (double)W_V[(size_t)(n * 64 + d) * HID + j] * vw[h * 64 + d];
      WVP[(size_t)blk * HID + j] = s;
    }
  } else {
    int r = blk - 256;
    int m = r >> 4, h = r & 15;
    for (int o = t; o < HID; o += 256) {
      double s = 0.0;
      for (int d = 0; d < 64; d++)
        s += ow[h * 64 + d] * (double)W_O[(size_t)o * HID + m * 64 + d];
      G[(size_t)r * HID + o] = (float)s;
    }
  }
}

// ---------------- K1: Q/K projection (fp64 accumulate) + per-head LayerNorm, store fp64 -------------
// Paired-plane fp64 LDS + (256,4) pin (r15-verified best).
__global__ __launch_bounds__(256, 4) void k_proj_qk(
    const float* __restrict__ x, const float* __restrict__ W_Q, const float* __restrict__ W_K,
    const float* __restrict__ qw, const float* __restrict__ qb,
    const float* __restrict__ kw, const float* __restrict__ kb,
    double* __restrict__ Qh, double* __restrict__ Kh) {
  __shared__ double smem[4352];   // planes A0|A1|B0|B1, each [32][34]; Cs[64][65] overlays
  __shared__ double red[64][4];
  double (*Cs)[65] = (double(*)[65])smem;

  int rt = blockIdx.x, ot = blockIdx.y;
  bool isQ = (ot < 16);
  const float* W = isQ ? W_Q : W_K;
  int head = isQ ? ot : ot - 16;
  int o0 = head * 64;
  int t = threadIdx.x;
  int tr = t >> 4, tc = t & 15;

  double acc[4][4];
  #pragma unroll
  for (int i = 0; i < 4; i++)
    #pragma unroll
    for (int j = 0; j < 4; j++) acc[i][j] = 0.0;

  for (int k0 = 0; k0 < HID; k0 += 32) {
    #pragma unroll
    for (int i = 0; i < 8; i++) {
      int idx = t + i * 256;
      int r = idx >> 5, c = idx & 31;
      int plane = (r >> 1) & 1;
      int slot  = ((r >> 2) << 1) | (r & 1);
      smem[plane * 1088 + c * 34 + slot]        = (double)x[(size_t)(rt * 64 + r) * HID + k0 + c];
      smem[2176 + plane * 1088 + c * 34 + slot] = (double)W[(size_t)(o0 + r) * HID + k0 + c];
    }
    __syncthreads();
    #pragma unroll 1
    for (int kk = 0; kk < 32; kk++) {
      double2 a01 = *(const double2*)&smem[kk * 34 + 2 * tr];
      double2 a23 = *(const double2*)&smem[1088 + kk * 34 + 2 * tr];
      double2 b01 = *(const double2*)&smem[2176 + kk * 34 + 2 * tc];
      double2 b23 = *(const double2*)&smem[3264 + kk * 34 + 2 * tc];
      double a[4], b[4];
      a[0] = a01.x; a[1] = a01.y; a[2] = a23.x; a[3] = a23.y;
      b[0] = b01.x; b[1] = b01.y; b[2] = b23.x; b[3] = b23.y;
      #pragma unroll
      for (int i = 0; i < 4; i++)
        #pragma unroll
        for (int j = 0; j < 4; j++) acc[i][j] = fma(a[i], b[j], acc[i][j]);
    }
    __syncthreads();
  }

  #pragma unroll
  for (int i = 0; i < 4; i++)
    #pragma unroll
    for (int j = 0; j < 4; j++) Cs[tr * 4 + i][tc * 4 + j] = acc[i][j];
  __syncthreads();

  // LayerNorm per row (64 values), fp64, two-pass like the reference
  int r = t >> 2, p = t & 3;
  double s = 0.0;
  for (int i = 0; i < 16; i++) s += Cs[r][p * 16 + i];
  red[r][p] = s;
  __syncthreads();
  double mu = (red[r][0] + red[r][1] + red[r][2] + red[r][3]) * (1.0 / 64.0);
  __syncthreads();
  double s2 = 0.0;
  for (int i = 0; i < 16; i++) { double dl = Cs[r][p * 16 + i] - mu; s2 += dl * dl; }
  red[r][p] = s2;
  __syncthreads();
  double var = (red[r][0] + red[r][1] + red[r][2] + red[r][3]) * (1.0 / 64.0);
  double inv = 1.0 / sqrt(var + 1e-5);

  int R = rt * 64 + r;
  int b = R >> 11, ss = R & 2047;
  const float* lw = isQ ? qw : kw;
  const float* lb = isQ ? qb : kb;
  double* outp = isQ ? Qh : Kh;
  size_t base = (((size_t)b * 16 + head) * SEQ + ss) * 64;
  for (int i = 0; i < 16; i++) {
    int d = p * 16 + i;
    outp[base + d] = (Cs[r][d] - mu) * inv * (double)lw[d] + (double)lb[d];
  }
}

// ---------------- K1b: Vp = x @ WVP^T (fp64 acc, fp64 store), layout [b][n][k][h] -------------------
__global__ __launch_bounds__(256) void k_proj_vp(
    const float* __restrict__ x, const double* __restrict__ WVP, double* __restrict__ Vp) {
  __shared__ double smem[4352];
  int rt = blockIdx.x, ot = blockIdx.y;
  int t = threadIdx.x, tr = t >> 4, tc = t & 15;

  double acc[4][4];
  #pragma unroll
  for (int i = 0; i < 4; i++)
    #pragma unroll
    for (int j = 0; j < 4; j++) acc[i][j] = 0.0;

  for (int k0 = 0; k0 < HID; k0 += 32) {
    #pragma unroll
    for (int i = 0; i < 8; i++) {
      int idx = t + i * 256;
      int r = idx >> 5, c = idx & 31;
      int plane = (r >> 1) & 1;
      int slot  = ((r >> 2) << 1) | (r & 1);
      smem[plane * 1088 + c * 34 + slot]        = (double)x[(size_t)(rt * 64 + r) * HID + k0 + c];
      smem[2176 + plane * 1088 + c * 34 + slot] = WVP[(size_t)(ot * 64 + r) * HID + k0 + c];
    }
    __syncthreads();
    #pragma unroll 1
    for (int kk = 0; kk < 32; kk++) {
      double2 a01 = *(const double2*)&smem[kk * 34 + 2 * tr];
      double2 a23 = *(const double2*)&smem[1088 + kk * 34 + 2 * tr];
      double2 b01 = *(const double2*)&smem[2176 + kk * 34 + 2 * tc];
      double2 b23 = *(const double2*)&smem[3264 + kk * 34 + 2 * tc];
      double a[4], b[4];
      a[0] = a01.x; a[1] = a01.y; a[2] = a23.x; a[3] = a23.y;
      b[0] = b01.x; b[1] = b01.y; b[2] = b23.x; b[3] = b23.y;
      #pragma unroll
      for (int i = 0; i < 4; i++)
        #pragma unroll
        for (int j = 0; j < 4; j++) acc[i][j] = fma(a[i], b[j], acc[i][j]);
    }
    __syncthreads();
  }
  #pragma unroll
  for (int i = 0; i < 4; i++) {
    int R = rt * 64 + tr * 4 + i;
    int b = R >> 11, k = R & 2047;
    #pragma unroll
    for (int j = 0; j < 4; j++) {
      int cc = ot * 64 + tc * 4 + j;
      int n = cc >> 4, h = cc & 15;
      Vp[((((size_t)b * 16 + n) * SEQ) + k) * 16 + h] = acc[i][j];
    }
  }
}

// ---------------- K2 (A): LDS-staged attention body — r14/r15-verified control ----------------------
__global__ __launch_bounds__(256, 2) void k_attn_a(
    const double* __restrict__ Qh, const double* __restrict__ Kh,
    const double* __restrict__ Vp, double* __restrict__ pnum, double* __restrict__ pden) {
  int kh = blockIdx.x;
  int qt = blockIdx.y;
  int bn = blockIdx.z;        // 0..15
  int t = threadIdx.x;
  int s = qt * 256 + t;
  int kspan = SEQ / gridDim.x;

  __shared__ double2 K2[64][32];
  __shared__ double2 V2[64][8];

  double2 q2[32];
  const double2* qp = (const double2*)(Qh + ((size_t)bn * SEQ + s) * 64);
  #pragma unroll
  for (int d = 0; d < 32; d++) q2[d] = qp[d];

  double2 num2[8];
  #pragma unroll
  for (int i = 0; i < 8; i++) { num2[i].x = 0.0; num2[i].y = 0.0; }
  double den = 0.0;

  int k0 = kh * kspan;
  for (int kc = 0; kc < kspan; kc += 64) {
    const double2* kb = (const double2*)(Kh + ((size_t)bn * SEQ + k0 + kc) * 64);
    #pragma unroll
    for (int i = 0; i < 8; i++) {
      int idx = t + i * 256;
      K2[idx >> 5][idx & 31] = kb[idx];
    }
    const double2* vb = (const double2*)(Vp + ((size_t)bn * SEQ + k0 + kc) * 16);
    #pragma unroll
    for (int i = 0; i < 2; i++) {
      int idx = t + i * 256;
      V2[idx >> 3][idx & 7] = vb[idx];
    }
    __syncthreads();
    #pragma unroll 1
    for (int kk = 0; kk < 64; kk += 4) {
      double s0 = 0.0, s1 = 0.0, s2 = 0.0, s3 = 0.0;
      #pragma unroll
      for (int d2 = 0; d2 < 32; d2++) {
        double2 qq = q2[d2];
        double2 k0v = K2[kk + 0][d2];
        double2 k1v = K2[kk + 1][d2];
        double2 k2v = K2[kk + 2][d2];
        double2 k3v = K2[kk + 3][d2];
        s0 = fma(qq.x, k0v.x, s0); s0 = fma(qq.y, k0v.y, s0);
        s1 = fma(qq.x, k1v.x, s1); s1 = fma(qq.y, k1v.y, s1);
        s2 = fma(qq.x, k2v.x, s2); s2 = fma(qq.y, k2v.y, s2);
        s3 = fma(qq.x, k3v.x, s3); s3 = fma(qq.y, k3v.y, s3);
      }
      double e0 = fast_exp(s0 * 0.125);
      double e1 = fast_exp(s1 * 0.125);
      double e2 = fast_exp(s2 * 0.125);
      double e3 = fast_exp(s3 * 0.125);
      den += (e0 + e1) + (e2 + e3);
      #pragma unroll
      for (int h2 = 0; h2 < 8; h2++) {
        double2 v0 = V2[kk + 0][h2];
        double2 v1 = V2[kk + 1][h2];
        double2 v2 = V2[kk + 2][h2];
        double2 v3 = V2[kk + 3][h2];
        double2 a = num2[h2];
        a.x = fma(e0, v0.x, a.x); a.x = fma(e1, v1.x, a.x);
        a.x = fma(e2, v2.x, a.x); a.x = fma(e3, v3.x, a.x);
        a.y = fma(e0, v0.y, a.y); a.y = fma(e1, v1.y, a.y);
        a.y = fma(e2, v2.y, a.y); a.y = fma(e3, v3.y, a.y);
        num2[h2] = a;
      }
    }
    __syncthreads();
  }
  size_t pb = ((size_t)kh * 32 + bn) * SEQ + s;
  pden[pb] = den;
  #pragma unroll
  for (int h2 = 0; h2 < 8; h2++) {
    pnum[pb * 16 + 2 * h2]     = num2[h2].x;
    pnum[pb * 16 + 2 * h2 + 1] = num2[h2].y;
  }
}

// ---------------- K2 (B): direct-global (scalar-path) attention body --------------------------------
// K/V addresses depend only on blockIdx/loop counters -> wave-uniform -> compiler can emit
// s_load + v_fma with SGPR operand, moving the whole K/V stream onto the idle SMEM pipe.
// No LDS, no barriers. Arithmetic (values + FMA order) bit-identical to body A.
__global__ __launch_bounds__(256, 2) void k_attn_b(
    const double* __restrict__ Qh, const double* __restrict__ Kh,
    const double* __restrict__ Vp, double* __restrict__ pnum, double* __restrict__ pden) {
  int kh = blockIdx.x;
  int qt = blockIdx.y;
  int bn = blockIdx.z + 16;   // 16..31
  int t = threadIdx.x;
  int s = qt * 256 + t;
  int kspan = SEQ / gridDim.x;

  double2 q2[32];
  const double2* qp = (const double2*)(Qh + ((size_t)bn * SEQ + s) * 64);
  #pragma unroll
  for (int d = 0; d < 32; d++) q2[d] = qp[d];

  double2 num2[8];
  #pragma unroll
  for (int i = 0; i < 8; i++) { num2[i].x = 0.0; num2[i].y = 0.0; }
  double den = 0.0;

  int k0 = kh * kspan;
  const double2* kb = (const double2*)(Kh + ((size_t)bn * SEQ + k0) * 64);
  const double2* vb = (const double2*)(Vp + ((size_t)bn * SEQ + k0) * 16);

  #pragma unroll 1
  for (int kk = 0; kk < kspan; kk += 4) {
    const double2* kb0 = kb + (size_t)(kk + 0) * 32;
    const double2* kb1 = kb + (size_t)(kk + 1) * 32;
    const double2* kb2 = kb + (size_t)(kk + 2) * 32;
    const double2* kb3 = kb + (size_t)(kk + 3) * 32;
    double s0 = 0.0, s1 = 0.0, s2 = 0.0, s3 = 0.0;
    #pragma unroll
    for (int d2 = 0; d2 < 32; d2++) {
      double2 qq = q2[d2];
      double2 k0v = kb0[d2];
      double2 k1v = kb1[d2];
      double2 k2v = kb2[d2];
      double2 k3v = kb3[d2];
      s0 = fma(qq.x, k0v.x, s0); s0 = fma(qq.y, k0v.y, s0);
      s1 = fma(qq.x, k1v.x, s1); s1 = fma(qq.y, k1v.y, s1);
      s2 = fma(qq.x, k2v.x, s2); s2 = fma(qq.y, k2v.y, s2);
      s3 = fma(qq.x, k3v.x, s3); s3 = fma(qq.y, k3v.y, s3);
    }
    double e0 = fast_exp(s0 * 0.125);
    double e1 = fast_exp(s1 * 0.125);
    double e2 = fast_exp(s2 * 0.125);
    double e3 = fast_exp(s3 * 0.125);
    den += (e0 + e1) + (e2 + e3);
    const double2* vb0 = vb + (size_t)(kk + 0) * 8;
    const double2* vb1 = vb + (size_t)(kk + 1) * 8;
    const double2* vb2 = vb + (size_t)(kk + 2) * 8;
    const double2* vb3 = vb + (size_t)(kk + 3) * 8;
    #pragma unroll
    for (int h2 = 0; h2 < 8; h2++) {
      double2 v0 = vb0[h2];
      double2 v1 = vb1[h2];
      double2 v2 = vb2[h2];
      double2 v3 = vb3[h2];
      double2 a = num2[h2];
      a.x = fma(e0, v0.x, a.x); a.x = fma(e1, v1.x, a.x);
      a.x = fma(e2, v2.x, a.x); a.x = fma(e3, v3.x, a.x);
      a.y = fma(e0, v0.y, a.y); a.y = fma(e1, v1.y, a.y);
      a.y = fma(e2, v2.y, a.y); a.y = fma(e3, v3.y, a.y);
      num2[h2] = a;
    }
  }
  size_t pb = ((size_t)kh * 32 + bn) * SEQ + s;
  pden[pb] = den;
  #pragma unroll
  for (int h2 = 0; h2 < 8; h2++) {
    pnum[pb * 16 + 2 * h2]     = num2[h2].x;
    pnum[pb * 16 + 2 * h2 + 1] = num2[h2].y;
  }
}

// ---------------- K2b: combine key splits, divide, scatter into z-row layout (fp64) -----------------
__global__ void k_combine(const double* __restrict__ pnum, const double* __restrict__ pden,
                          double* __restrict__ zrow, int nkh) {
  int id = blockIdx.x * 256 + threadIdx.x;  // bn*2048 + s, 65536 total
  int bn = id >> 11, s = id & 2047;
  int b = bn >> 4, n = bn & 15;
  double den = 0.0;
  for (int j = 0; j < nkh; j++) den += pden[(size_t)j * 65536 + id];
  int bp = b * 16 + (s >> 7);          // mixed "batch" index of context_flat
  int np = ((s & 127) << 4) | n;       // mixed candidate index
  for (int h = 0; h < 16; h++) {
    double nm = 0.0;
    for (int j = 0; j < nkh; j++) nm += pnum[((size_t)j * 65536 + id) * 16 + h];
    zrow[((size_t)bp * 16 + h) * 2048 + np] = nm / den;
  }
}

// ---------------- K3: exact top-128 per row via radix binary search on monotone uint64 keys ---------
__device__ inline unsigned long long dkey(double v) {
  unsigned long long u = (unsigned long long)__double_as_longlong(v);
  return (u & 0x8000000000000000ULL) ? ~u : (u | 0x8000000000000000ULL);
}

__global__ __launch_bounds__(256) void k_topk(const double* __restrict__ zrow,
                                              float* __restrict__ zs) {
  int row = blockIdx.x;  // (bp*16+h) in [0,512)
  int t = threadIdx.x;
  const double* src = zrow + (size_t)row * 2048;
  double v[8];
  unsigned long long key[8];
  #pragma unroll
  for (int i = 0; i < 8; i++) { v[i] = src[t + i * 256]; key[i] = dkey(v[i]); }

  __shared__ unsigned sh_cnt[4];
  __shared__ unsigned sh_cg[4], sh_ce[4];
  int w = t >> 6, lane = t & 63;

  unsigned long long lo = 0ULL, hi = 0xFFFFFFFFFFFFFFFFULL;
  while (lo < hi) {
    unsigned long long mid = lo + ((hi - lo) >> 1);
    unsigned c = 0;
    #pragma unroll
    for (int i = 0; i < 8; i++) c += (key[i] > mid) ? 1u : 0u;
    for (int off = 32; off; off >>= 1) c += __shfl_down(c, off);
    if (lane == 0) sh_cnt[w] = c;
    __syncthreads();
    unsigned total = sh_cnt[0] + sh_cnt[1] + sh_cnt[2] + sh_cnt[3];
    __syncthreads();
    if (total < TOPK) hi = mid; else lo = mid + 1;
  }
  unsigned long long tau = lo;

  unsigned cg = 0, ce = 0;
  #pragma unroll
  for (int i = 0; i < 8; i++) {
    cg += (key[i] > tau) ? 1u : 0u;
    ce += (key[i] == tau) ? 1u : 0u;
  }
  for (int off = 32; off; off >>= 1) { cg += __shfl_down(cg, off); ce += __shfl_down(ce, off); }
  if (lane == 0) { sh_cg[w] = cg; sh_ce[w] = ce; }
  __syncthreads();
  unsigned c_gt = sh_cg[0] + sh_cg[1] + sh_cg[2] + sh_cg[3];
  unsigned c_eq = sh_ce[0] + sh_ce[1] + sh_ce[2] + sh_ce[3];
  unsigned need = TOPK - c_gt;

  unsigned idxThr = 2048;
  if (c_eq > need) {
    unsigned l2 = 0, h2 = 2048;
    while (l2 < h2) {
      unsigned m2 = (l2 + h2) >> 1;
      unsigned c = 0;
      #pragma unroll
      for (int i = 0; i < 8; i++) {
        unsigned idx = (unsigned)(t + i * 256);
        c += (key[i] == tau && idx < m2) ? 1u : 0u;
      }
      for (int off = 32; off; off >>= 1) c += __shfl_down(c, off);
      if (lane == 0) sh_cnt[w] = c;
      __syncthreads();
      unsigned tot = sh_cnt[0] + sh_cnt[1] + sh_cnt[2] + sh_cnt[3];
      __syncthreads();
      if (tot >= need) h2 = m2; else l2 = m2 + 1;
    }
    idxThr = l2;
  }

  float* dst = zs + (size_t)row * 2048;
  #pragma unroll
  for (int i = 0; i < 8; i++) {
    unsigned idx = (unsigned)(t + i * 256);
    bool keep = (key[i] > tau) ||
                (key[i] == tau && (c_eq <= need || idx < idxThr));
    dst[idx] = keep ? (float)v[i] : 0.0f;
  }
}

// ---------------- K4: out = Z2 @ G  (4096 x 256 x 1024, fp32) ---------------------------------------
__global__ __launch_bounds__(256) void k_out(const float* __restrict__ zs,
                                             const float* __restrict__ G,
                                             float* __restrict__ out) {
  __shared__ float Al[64][65];
  __shared__ float Bl[64][65];
  int rt = blockIdx.x, ot = blockIdx.y;
  int t = threadIdx.x, tr = t >> 4, tc = t & 15;
  int Rb = rt * 64;
  int b = Rb >> 11, s0 = Rb & 2047;

  float acc[4][4];
  #pragma unroll
  for (int i = 0; i < 4; i++)
    #pragma unroll
    for (int j = 0; j < 4; j++) acc[i][j] = 0.0f;

  for (int kc = 0; kc < 256; kc += 64) {
    #pragma unroll
    for (int i = 0; i < 16; i++) {
      int idx = t + i * 256;
      int c = idx >> 6, r = idx & 63;
      int cc = kc + c;
      Al[r][c] = zs[(((size_t)(b * 16 + (cc >> 4))) * 16 + (cc & 15)) * 2048 + s0 + r];
      Bl[c][r] = G[(size_t)(kc + c) * HID + ot * 64 + r];
    }
    __syncthreads();
    #pragma unroll 1
    for (int kk = 0; kk < 64; kk++) {
      float a[4], bb[4];
      #pragma unroll
      for (int i = 0; i < 4; i++) a[i] = Al[tr * 4 + i][kk];
      #pragma unroll
      for (int j = 0; j < 4; j++) bb[j] = Bl[kk][tc * 4 + j];
      #pragma unroll
      for (int i = 0; i < 4; i++)
        #pragma unroll
        for (int j = 0; j < 4; j++) acc[i][j] = fmaf(a[i], bb[j], acc[i][j]);
    }
    __syncthreads();
  }
  #pragma unroll
  for (int i = 0; i < 4; i++) {
    int R = Rb + tr * 4 + i;
    #pragma unroll
    for (int j = 0; j < 4; j++)
      out[(size_t)R * HID + ot * 64 + tc * 4 + j] = acc[i][j];
  }
}

// ---------------- launch ----------------------------------------------------------------------------
extern "C" void kernel_launch(void* const* d_in, const int* in_sizes, int n_in,
                              void* d_out, int out_size, void* d_ws, size_t ws_size,
                              hipStream_t stream) {
  const float* x   = (const float*)d_in[0];
  const float* W_Q = (const float*)d_in[1];
  const float* W_K = (const float*)d_in[2];
  const float* W_V = (const float*)d_in[3];
  const float* W_O = (const float*)d_in[4];
  const float* qw  = (const float*)d_in[5];
  const float* qb  = (const float*)d_in[6];
  const float* kw  = (const float*)d_in[7];
  const float* kb  = (const float*)d_in[8];
  const float* sWV = (const float*)d_in[9];
  const float* sWO = (const float*)d_in[10];
  float* out = (float*)d_out;
  char* ws = (char*)d_ws;

  // 4-way key split (r6-verified to fit); fall back to 2-way if workspace is smaller.
  const size_t NEED4 = 114311168ULL;
  int nkh = (ws_size >= NEED4) ? 4 : 2;

  double* Qh   = (double*)(ws + 0);          // 33,554,432
  double* Kh   = (double*)(ws + 33554432ULL);// 33,554,432
  double* Vp   = (double*)(ws + 67108864ULL);// 8,388,608
  double* WVP  = (double*)(ws + 75497472ULL);// 2,097,152
  float*  G    = (float*) (ws + 77594624ULL);// 1,048,576
  double* vw   = (double*)(ws + 78643200ULL);// 8,192
  double* ow   = (double*)(ws + 78651392ULL);// 8,192
  double* pnum = (double*)(ws + 78659584ULL);// nkh * 8,388,608
  double* pden = (double*)(ws + 78659584ULL + (size_t)nkh * 8388608ULL); // nkh * 524,288
  double* zrow = (double*)(ws + 0);          // overlay: 8,388,608
  float*  zs   = (float*) (ws + 8388608ULL); // overlay: 4,194,304

  k_prep_means<<<dim3(1), dim3(256), 0, stream>>>(sWV, sWO, vw, ow);
  k_prep_wvp_g<<<dim3(512), dim3(256), 0, stream>>>(W_V, W_O, vw, ow, WVP, G);
  k_proj_qk<<<dim3(64, 32), dim3(256), 0, stream>>>(x, W_Q, W_K, qw, qb, kw, kb, Qh, Kh);
  k_proj_vp<<<dim3(64, 4), dim3(256), 0, stream>>>(x, WVP, Vp);
  // A/B: bn 0..15 = LDS-staged control, bn 16..31 = direct-global (scalar-path) candidate
  k_attn_a<<<dim3(nkh, 8, 16), dim3(256), 0, stream>>>(Qh, Kh, Vp, pnum, pden);
  k_attn_b<<<dim3(nkh, 8, 16), dim3(256), 0, stream>>>(Qh, Kh, Vp, pnum, pden);
  k_combine<<<dim3(256), dim3(256), 0, stream>>>(pnum, pden, zrow, nkh);
  k_topk<<<dim3(512), dim3(256), 0, stream>>>(zrow, zs);
  k_out<<<dim3(64, 16), dim3(256), 0, stream>>>(zs, G, out);
}

// Round 17
// 1416.326 us; speedup vs baseline: 1.2881x; 1.2881x over previous
//
#include <hip/hip_runtime.h>
#include <math.h>

// Problem constants
#define NB   2
#define SEQ  2048
#define NHD  16
#define HDD  64
#define HID  1024
#define TOPK 128

// Branch-free fp64 exp for |x| <= ~60 (here |x| <= 8). Cody-Waite + degree-12 Taylor (r14-verified).
__device__ __forceinline__ double fast_exp(double x) {
  double n = rint(x * 1.44269504088896340736);
  double r = fma(n, -6.93147180369123816490e-01, x);
  r = fma(n, -1.90821492927058770002e-10, r);
  double p = 2.08767569878680989792e-09;
  p = fma(p, r, 2.50521083854417187751e-08);
  p = fma(p, r, 2.75573192239858906526e-07);
  p = fma(p, r, 2.75573192239858882510e-06);
  p = fma(p, r, 2.48015873015873015873e-05);
  p = fma(p, r, 1.98412698412698412698e-04);
  p = fma(p, r, 1.38888888888888888889e-03);
  p = fma(p, r, 8.33333333333333333333e-03);
  p = fma(p, r, 4.16666666666666666667e-02);
  p = fma(p, r, 1.66666666666666666667e-01);
  p = fma(p, r, 5.00000000000000000000e-01);
  p = fma(p, r, 1.0);
  p = fma(p, r, 1.0);
  long long k = (long long)(int)n;
  double sc = __longlong_as_double((k + 1023LL) << 52);
  return p * sc;
}

// ---------------- K0a: vw = mean(sparse_W_V, axis=2), ow = mean(sparse_W_O, axis=1) (fp64) ----------
__global__ void k_prep_means(const float* __restrict__ sWV, const float* __restrict__ sWO,
                             double* __restrict__ vw, double* __restrict__ ow) {
  int t = threadIdx.x;
  for (int o = t; o < NHD * HDD; o += 256) {
    const float* p = sWV + (size_t)o * TOPK;
    double s = 0.0;
    for (int i = 0; i < TOPK; i++) s += (double)p[i];
    vw[o] = s * (1.0 / 128.0);
    int h = o >> 6, d = o & 63;
    const float* q = sWO + ((size_t)h * TOPK) * HDD + d;
    double s2 = 0.0;
    for (int i = 0; i < TOPK; i++) s2 += (double)q[(size_t)i * HDD];
    ow[o] = s2 * (1.0 / 128.0);
  }
}

// ---------------- K0b: WVP[(n*16+h), j] = sum_d W_V[n*64+d, j]*vw[h,d]  (fp64)
//                       G[(m*16+h), o]  = sum_d ow[h,d]*W_O[o, m*64+d]  (fp32) ----------------------
__global__ void k_prep_wvp_g(const float* __restrict__ W_V, const float* __restrict__ W_O,
                             const double* __restrict__ vw, const double* __restrict__ ow,
                             double* __restrict__ WVP, float* __restrict__ G) {
  int blk = blockIdx.x;
  int t = threadIdx.x;
  if (blk < 256) {
    int n = blk >> 4, h = blk & 15;
    for (int j = t; j < HID; j += 256) {
      double s = 0.0;
      for (int d = 0; d < 64; d++)
        s += (double)W_V[(size_t)(n * 64 + d) * HID + j] * vw[h * 64 + d];
      WVP[(size_t)blk * HID + j] = s;
    }
  } else {
    int r = blk - 256;
    int m = r >> 4, h = r & 15;
    for (int o = t; o < HID; o += 256) {
      double s = 0.0;
      for (int d = 0; d < 64; d++)
        s += ow[h * 64 + d] * (double)W_O[(size_t)o * HID + m * 64 + d];
      G[(size_t)r * HID + o] = (float)s;
    }
  }
}

// ---------------- K1: Q/K projection (fp64 accumulate) + per-head LayerNorm, store fp64 -------------
// Paired-plane fp64 LDS + (256,4) pin (r15-verified best).
__global__ __launch_bounds__(256, 4) void k_proj_qk(
    const float* __restrict__ x, const float* __restrict__ W_Q, const float* __restrict__ W_K,
    const float* __restrict__ qw, const float* __restrict__ qb,
    const float* __restrict__ kw, const float* __restrict__ kb,
    double* __restrict__ Qh, double* __restrict__ Kh) {
  __shared__ double smem[4352];   // planes A0|A1|B0|B1, each [32][34]; Cs[64][65] overlays
  __shared__ double red[64][4];
  double (*Cs)[65] = (double(*)[65])smem;

  int rt = blockIdx.x, ot = blockIdx.y;
  bool isQ = (ot < 16);
  const float* W = isQ ? W_Q : W_K;
  int head = isQ ? ot : ot - 16;
  int o0 = head * 64;
  int t = threadIdx.x;
  int tr = t >> 4, tc = t & 15;

  double acc[4][4];
  #pragma unroll
  for (int i = 0; i < 4; i++)
    #pragma unroll
    for (int j = 0; j < 4; j++) acc[i][j] = 0.0;

  for (int k0 = 0; k0 < HID; k0 += 32) {
    #pragma unroll
    for (int i = 0; i < 8; i++) {
      int idx = t + i * 256;
      int r = idx >> 5, c = idx & 31;
      int plane = (r >> 1) & 1;
      int slot  = ((r >> 2) << 1) | (r & 1);
      smem[plane * 1088 + c * 34 + slot]        = (double)x[(size_t)(rt * 64 + r) * HID + k0 + c];
      smem[2176 + plane * 1088 + c * 34 + slot] = (double)W[(size_t)(o0 + r) * HID + k0 + c];
    }
    __syncthreads();
    #pragma unroll 1
    for (int kk = 0; kk < 32; kk++) {
      double2 a01 = *(const double2*)&smem[kk * 34 + 2 * tr];
      double2 a23 = *(const double2*)&smem[1088 + kk * 34 + 2 * tr];
      double2 b01 = *(const double2*)&smem[2176 + kk * 34 + 2 * tc];
      double2 b23 = *(const double2*)&smem[3264 + kk * 34 + 2 * tc];
      double a[4], b[4];
      a[0] = a01.x; a[1] = a01.y; a[2] = a23.x; a[3] = a23.y;
      b[0] = b01.x; b[1] = b01.y; b[2] = b23.x; b[3] = b23.y;
      #pragma unroll
      for (int i = 0; i < 4; i++)
        #pragma unroll
        for (int j = 0; j < 4; j++) acc[i][j] = fma(a[i], b[j], acc[i][j]);
    }
    __syncthreads();
  }

  #pragma unroll
  for (int i = 0; i < 4; i++)
    #pragma unroll
    for (int j = 0; j < 4; j++) Cs[tr * 4 + i][tc * 4 + j] = acc[i][j];
  __syncthreads();

  // LayerNorm per row (64 values), fp64, two-pass like the reference
  int r = t >> 2, p = t & 3;
  double s = 0.0;
  for (int i = 0; i < 16; i++) s += Cs[r][p * 16 + i];
  red[r][p] = s;
  __syncthreads();
  double mu = (red[r][0] + red[r][1] + red[r][2] + red[r][3]) * (1.0 / 64.0);
  __syncthreads();
  double s2 = 0.0;
  for (int i = 0; i < 16; i++) { double dl = Cs[r][p * 16 + i] - mu; s2 += dl * dl; }
  red[r][p] = s2;
  __syncthreads();
  double var = (red[r][0] + red[r][1] + red[r][2] + red[r][3]) * (1.0 / 64.0);
  double inv = 1.0 / sqrt(var + 1e-5);

  int R = rt * 64 + r;
  int b = R >> 11, ss = R & 2047;
  const float* lw = isQ ? qw : kw;
  const float* lb = isQ ? qb : kb;
  double* outp = isQ ? Qh : Kh;
  size_t base = (((size_t)b * 16 + head) * SEQ + ss) * 64;
  for (int i = 0; i < 16; i++) {
    int d = p * 16 + i;
    outp[base + d] = (Cs[r][d] - mu) * inv * (double)lw[d] + (double)lb[d];
  }
}

// ---------------- K1b: Vp = x @ WVP^T (fp64 acc, fp64 store), layout [b][n][k][h] -------------------
__global__ __launch_bounds__(256) void k_proj_vp(
    const float* __restrict__ x, const double* __restrict__ WVP, double* __restrict__ Vp) {
  __shared__ double smem[4352];
  int rt = blockIdx.x, ot = blockIdx.y;
  int t = threadIdx.x, tr = t >> 4, tc = t & 15;

  double acc[4][4];
  #pragma unroll
  for (int i = 0; i < 4; i++)
    #pragma unroll
    for (int j = 0; j < 4; j++) acc[i][j] = 0.0;

  for (int k0 = 0; k0 < HID; k0 += 32) {
    #pragma unroll
    for (int i = 0; i < 8; i++) {
      int idx = t + i * 256;
      int r = idx >> 5, c = idx & 31;
      int plane = (r >> 1) & 1;
      int slot  = ((r >> 2) << 1) | (r & 1);
      smem[plane * 1088 + c * 34 + slot]        = (double)x[(size_t)(rt * 64 + r) * HID + k0 + c];
      smem[2176 + plane * 1088 + c * 34 + slot] = WVP[(size_t)(ot * 64 + r) * HID + k0 + c];
    }
    __syncthreads();
    #pragma unroll 1
    for (int kk = 0; kk < 32; kk++) {
      double2 a01 = *(const double2*)&smem[kk * 34 + 2 * tr];
      double2 a23 = *(const double2*)&smem[1088 + kk * 34 + 2 * tr];
      double2 b01 = *(const double2*)&smem[2176 + kk * 34 + 2 * tc];
      double2 b23 = *(const double2*)&smem[3264 + kk * 34 + 2 * tc];
      double a[4], b[4];
      a[0] = a01.x; a[1] = a01.y; a[2] = a23.x; a[3] = a23.y;
      b[0] = b01.x; b[1] = b01.y; b[2] = b23.x; b[3] = b23.y;
      #pragma unroll
      for (int i = 0; i < 4; i++)
        #pragma unroll
        for (int j = 0; j < 4; j++) acc[i][j] = fma(a[i], b[j], acc[i][j]);
    }
    __syncthreads();
  }
  #pragma unroll
  for (int i = 0; i < 4; i++) {
    int R = rt * 64 + tr * 4 + i;
    int b = R >> 11, k = R & 2047;
    #pragma unroll
    for (int j = 0; j < 4; j++) {
      int cc = ot * 64 + tc * 4 + j;
      int n = cc >> 4, h = cc & 15;
      Vp[((((size_t)b * 16 + n) * SEQ) + k) * 16 + h] = acc[i][j];
    }
  }
}

// ---------------- K2: attention, no-max softmax accumulation in fp64 --------------------------------
// r6/r12/r14 LDS-staged body (the verified optimum; direct-global path falsified 1.7x slower in r16's
// A/B). One change vs r15: #pragma unroll 2 on the kk loop — lets the scheduler interleave PV(i)
// with QK(i+1) (data-independent chains) to cover part of the dependency-stall half of the 836us.
// Values and per-accumulator FMA order unchanged.
__global__ __launch_bounds__(256, 2) void k_attn(
    const double* __restrict__ Qh, const double* __restrict__ Kh,
    const double* __restrict__ Vp, double* __restrict__ pnum, double* __restrict__ pden) {
  int kh = blockIdx.x;  // key split index
  int qt = blockIdx.y;  // query tile
  int bn = blockIdx.z;  // (b*16+n)
  int t = threadIdx.x;
  int s = qt * 256 + t;
  int kspan = SEQ / gridDim.x;

  __shared__ double2 K2[64][32];   // [key][d/2]
  __shared__ double2 V2[64][8];    // [key][h/2]

  double2 q2[32];
  const double2* qp = (const double2*)(Qh + ((size_t)bn * SEQ + s) * 64);
  #pragma unroll
  for (int d = 0; d < 32; d++) q2[d] = qp[d];

  double2 num2[8];
  #pragma unroll
  for (int i = 0; i < 8; i++) { num2[i].x = 0.0; num2[i].y = 0.0; }
  double den = 0.0;

  int k0 = kh * kspan;
  for (int kc = 0; kc < kspan; kc += 64) {
    const double2* kb = (const double2*)(Kh + ((size_t)bn * SEQ + k0 + kc) * 64);
    #pragma unroll
    for (int i = 0; i < 8; i++) {
      int idx = t + i * 256;             // 2048 double2
      K2[idx >> 5][idx & 31] = kb[idx];
    }
    const double2* vb = (const double2*)(Vp + ((size_t)bn * SEQ + k0 + kc) * 16);
    #pragma unroll
    for (int i = 0; i < 2; i++) {
      int idx = t + i * 256;             // 512 double2
      V2[idx >> 3][idx & 7] = vb[idx];
    }
    __syncthreads();
    #pragma unroll 2
    for (int kk = 0; kk < 64; kk += 4) {
      double s0 = 0.0, s1 = 0.0, s2 = 0.0, s3 = 0.0;
      #pragma unroll
      for (int d2 = 0; d2 < 32; d2++) {
        double2 qq = q2[d2];
        double2 k0v = K2[kk + 0][d2];
        double2 k1v = K2[kk + 1][d2];
        double2 k2v = K2[kk + 2][d2];
        double2 k3v = K2[kk + 3][d2];
        s0 = fma(qq.x, k0v.x, s0); s0 = fma(qq.y, k0v.y, s0);
        s1 = fma(qq.x, k1v.x, s1); s1 = fma(qq.y, k1v.y, s1);
        s2 = fma(qq.x, k2v.x, s2); s2 = fma(qq.y, k2v.y, s2);
        s3 = fma(qq.x, k3v.x, s3); s3 = fma(qq.y, k3v.y, s3);
      }
      double e0 = fast_exp(s0 * 0.125);
      double e1 = fast_exp(s1 * 0.125);
      double e2 = fast_exp(s2 * 0.125);
      double e3 = fast_exp(s3 * 0.125);
      den += (e0 + e1) + (e2 + e3);
      #pragma unroll
      for (int h2 = 0; h2 < 8; h2++) {
        double2 v0 = V2[kk + 0][h2];
        double2 v1 = V2[kk + 1][h2];
        double2 v2 = V2[kk + 2][h2];
        double2 v3 = V2[kk + 3][h2];
        double2 a = num2[h2];
        a.x = fma(e0, v0.x, a.x); a.x = fma(e1, v1.x, a.x);
        a.x = fma(e2, v2.x, a.x); a.x = fma(e3, v3.x, a.x);
        a.y = fma(e0, v0.y, a.y); a.y = fma(e1, v1.y, a.y);
        a.y = fma(e2, v2.y, a.y); a.y = fma(e3, v3.y, a.y);
        num2[h2] = a;
      }
    }
    __syncthreads();
  }
  size_t pb = ((size_t)kh * 32 + bn) * SEQ + s;
  pden[pb] = den;
  #pragma unroll
  for (int h2 = 0; h2 < 8; h2++) {
    pnum[pb * 16 + 2 * h2]     = num2[h2].x;
    pnum[pb * 16 + 2 * h2 + 1] = num2[h2].y;
  }
}

// ---------------- K2b: combine key splits, divide, scatter into z-row layout (fp64) -----------------
__global__ void k_combine(const double* __restrict__ pnum, const double* __restrict__ pden,
                          double* __restrict__ zrow, int nkh) {
  int id = blockIdx.x * 256 + threadIdx.x;  // bn*2048 + s, 65536 total
  int bn = id >> 11, s = id & 2047;
  int b = bn >> 4, n = bn & 15;
  double den = 0.0;
  for (int j = 0; j < nkh; j++) den += pden[(size_t)j * 65536 + id];
  int bp = b * 16 + (s >> 7);          // mixed "batch" index of context_flat
  int np = ((s & 127) << 4) | n;       // mixed candidate index
  for (int h = 0; h < 16; h++) {
    double nm = 0.0;
    for (int j = 0; j < nkh; j++) nm += pnum[((size_t)j * 65536 + id) * 16 + h];
    zrow[((size_t)bp * 16 + h) * 2048 + np] = nm / den;
  }
}

// ---------------- K3: exact top-128 per row via radix binary search on monotone uint64 keys ---------
__device__ inline unsigned long long dkey(double v) {
  unsigned long long u = (unsigned long long)__double_as_longlong(v);
  return (u & 0x8000000000000000ULL) ? ~u : (u | 0x8000000000000000ULL);
}

__global__ __launch_bounds__(256) void k_topk(const double* __restrict__ zrow,
                                              float* __restrict__ zs) {
  int row = blockIdx.x;  // (bp*16+h) in [0,512)
  int t = threadIdx.x;
  const double* src = zrow + (size_t)row * 2048;
  double v[8];
  unsigned long long key[8];
  #pragma unroll
  for (int i = 0; i < 8; i++) { v[i] = src[t + i * 256]; key[i] = dkey(v[i]); }

  __shared__ unsigned sh_cnt[4];
  __shared__ unsigned sh_cg[4], sh_ce[4];
  int w = t >> 6, lane = t & 63;

  unsigned long long lo = 0ULL, hi = 0xFFFFFFFFFFFFFFFFULL;
  while (lo < hi) {
    unsigned long long mid = lo + ((hi - lo) >> 1);
    unsigned c = 0;
    #pragma unroll
    for (int i = 0; i < 8; i++) c += (key[i] > mid) ? 1u : 0u;
    for (int off = 32; off; off >>= 1) c += __shfl_down(c, off);
    if (lane == 0) sh_cnt[w] = c;
    __syncthreads();
    unsigned total = sh_cnt[0] + sh_cnt[1] + sh_cnt[2] + sh_cnt[3];
    __syncthreads();
    if (total < TOPK) hi = mid; else lo = mid + 1;
  }
  unsigned long long tau = lo;

  unsigned cg = 0, ce = 0;
  #pragma unroll
  for (int i = 0; i < 8; i++) {
    cg += (key[i] > tau) ? 1u : 0u;
    ce += (key[i] == tau) ? 1u : 0u;
  }
  for (int off = 32; off; off >>= 1) { cg += __shfl_down(cg, off); ce += __shfl_down(ce, off); }
  if (lane == 0) { sh_cg[w] = cg; sh_ce[w] = ce; }
  __syncthreads();
  unsigned c_gt = sh_cg[0] + sh_cg[1] + sh_cg[2] + sh_cg[3];
  unsigned c_eq = sh_ce[0] + sh_ce[1] + sh_ce[2] + sh_ce[3];
  unsigned need = TOPK - c_gt;

  unsigned idxThr = 2048;
  if (c_eq > need) {
    unsigned l2 = 0, h2 = 2048;
    while (l2 < h2) {
      unsigned m2 = (l2 + h2) >> 1;
      unsigned c = 0;
      #pragma unroll
      for (int i = 0; i < 8; i++) {
        unsigned idx = (unsigned)(t + i * 256);
        c += (key[i] == tau && idx < m2) ? 1u : 0u;
      }
      for (int off = 32; off; off >>= 1) c += __shfl_down(c, off);
      if (lane == 0) sh_cnt[w] = c;
      __syncthreads();
      unsigned tot = sh_cnt[0] + sh_cnt[1] + sh_cnt[2] + sh_cnt[3];
      __syncthreads();
      if (tot >= need) h2 = m2; else l2 = m2 + 1;
    }
    idxThr = l2;
  }

  float* dst = zs + (size_t)row * 2048;
  #pragma unroll
  for (int i = 0; i < 8; i++) {
    unsigned idx = (unsigned)(t + i * 256);
    bool keep = (key[i] > tau) ||
                (key[i] == tau && (c_eq <= need || idx < idxThr));
    dst[idx] = keep ? (float)v[i] : 0.0f;
  }
}

// ---------------- K4: out = Z2 @ G  (4096 x 256 x 1024, fp32) ---------------------------------------
__global__ __launch_bounds__(256) void k_out(const float* __restrict__ zs,
                                             const float* __restrict__ G,
                                             float* __restrict__ out) {
  __shared__ float Al[64][65];
  __shared__ float Bl[64][65];
  int rt = blockIdx.x, ot = blockIdx.y;
  int t = threadIdx.x, tr = t >> 4, tc = t & 15;
  int Rb = rt * 64;
  int b = Rb >> 11, s0 = Rb & 2047;

  float acc[4][4];
  #pragma unroll
  for (int i = 0; i < 4; i++)
    #pragma unroll
    for (int j = 0; j < 4; j++) acc[i][j] = 0.0f;

  for (int kc = 0; kc < 256; kc += 64) {
    #pragma unroll
    for (int i = 0; i < 16; i++) {
      int idx = t + i * 256;
      int c = idx >> 6, r = idx & 63;
      int cc = kc + c;
      Al[r][c] = zs[(((size_t)(b * 16 + (cc >> 4))) * 16 + (cc & 15)) * 2048 + s0 + r];
      Bl[c][r] = G[(size_t)(kc + c) * HID + ot * 64 + r];
    }
    __syncthreads();
    #pragma unroll 1
    for (int kk = 0; kk < 64; kk++) {
      float a[4], bb[4];
      #pragma unroll
      for (int i = 0; i < 4; i++) a[i] = Al[tr * 4 + i][kk];
      #pragma unroll
      for (int j = 0; j < 4; j++) bb[j] = Bl[kk][tc * 4 + j];
      #pragma unroll
      for (int i = 0; i < 4; i++)
        #pragma unroll
        for (int j = 0; j < 4; j++) acc[i][j] = fmaf(a[i], bb[j], acc[i][j]);
    }
    __syncthreads();
  }
  #pragma unroll
  for (int i = 0; i < 4; i++) {
    int R = Rb + tr * 4 + i;
    #pragma unroll
    for (int j = 0; j < 4; j++)
      out[(size_t)R * HID + ot * 64 + tc * 4 + j] = acc[i][j];
  }
}

// ---------------- launch ----------------------------------------------------------------------------
extern "C" void kernel_launch(void* const* d_in, const int* in_sizes, int n_in,
                              void* d_out, int out_size, void* d_ws, size_t ws_size,
                              hipStream_t stream) {
  const float* x   = (const float*)d_in[0];
  const float* W_Q = (const float*)d_in[1];
  const float* W_K = (const float*)d_in[2];
  const float* W_V = (const float*)d_in[3];
  const float* W_O = (const float*)d_in[4];
  const float* qw  = (const float*)d_in[5];
  const float* qb  = (const float*)d_in[6];
  const float* kw  = (const float*)d_in[7];
  const float* kb  = (const float*)d_in[8];
  const float* sWV = (const float*)d_in[9];
  const float* sWO = (const float*)d_in[10];
  float* out = (float*)d_out;
  char* ws = (char*)d_ws;

  // 4-way key split (r6-verified to fit); fall back to 2-way if workspace is smaller.
  const size_t NEED4 = 114311168ULL;
  int nkh = (ws_size >= NEED4) ? 4 : 2;

  double* Qh   = (double*)(ws + 0);          // 33,554,432
  double* Kh   = (double*)(ws + 33554432ULL);// 33,554,432
  double* Vp   = (double*)(ws + 67108864ULL);// 8,388,608
  double* WVP  = (double*)(ws + 75497472ULL);// 2,097,152
  float*  G    = (float*) (ws + 77594624ULL);// 1,048,576
  double* vw   = (double*)(ws + 78643200ULL);// 8,192
  double* ow   = (double*)(ws + 78651392ULL);// 8,192
  double* pnum = (double*)(ws + 78659584ULL);// nkh * 8,388,608
  double* pden = (double*)(ws + 78659584ULL + (size_t)nkh * 8388608ULL); // nkh * 524,288
  double* zrow = (double*)(ws + 0);          // overlay: 8,388,608
  float*  zs   = (float*) (ws + 8388608ULL); // overlay: 4,194,304

  k_prep_means<<<dim3(1), dim3(256), 0, stream>>>(sWV, sWO, vw, ow);
  k_prep_wvp_g<<<dim3(512), dim3(256), 0, stream>>>(W_V, W_O, vw, ow, WVP, G);
  k_proj_qk<<<dim3(64, 32), dim3(256), 0, stream>>>(x, W_Q, W_K, qw, qb, kw, kb, Qh, Kh);
  k_proj_vp<<<dim3(64, 4), dim3(256), 0, stream>>>(x, WVP, Vp);
  k_attn<<<dim3(nkh, 8, 32), dim3(256), 0, stream>>>(Qh, Kh, Vp, pnum, pden);
  k_combine<<<dim3(256), dim3(256), 0, stream>>>(pnum, pden, zrow, nkh);
  k_topk<<<dim3(512), dim3(256), 0, stream>>>(zrow, zs);
  k_out<<<dim3(64, 16), dim3(256), 0, stream>>>(zs, G, out);
}

// Round 18
// 1415.630 us; speedup vs baseline: 1.2888x; 1.0005x over previous
//
#include <hip/hip_runtime.h>
#include <math.h>

// Problem constants
#define NB   2
#define SEQ  2048
#define NHD  16
#define HDD  64
#define HID  1024
#define TOPK 128

// Branch-free fp64 exp for |x| <= ~60 (here |x| <= 8). Cody-Waite + degree-12 Taylor (r14-verified).
__device__ __forceinline__ double fast_exp(double x) {
  double n = rint(x * 1.44269504088896340736);
  double r = fma(n, -6.93147180369123816490e-01, x);
  r = fma(n, -1.90821492927058770002e-10, r);
  double p = 2.08767569878680989792e-09;
  p = fma(p, r, 2.50521083854417187751e-08);
  p = fma(p, r, 2.75573192239858906526e-07);
  p = fma(p, r, 2.75573192239858882510e-06);
  p = fma(p, r, 2.48015873015873015873e-05);
  p = fma(p, r, 1.98412698412698412698e-04);
  p = fma(p, r, 1.38888888888888888889e-03);
  p = fma(p, r, 8.33333333333333333333e-03);
  p = fma(p, r, 4.16666666666666666667e-02);
  p = fma(p, r, 1.66666666666666666667e-01);
  p = fma(p, r, 5.00000000000000000000e-01);
  p = fma(p, r, 1.0);
  p = fma(p, r, 1.0);
  long long k = (long long)(int)n;
  double sc = __longlong_as_double((k + 1023LL) << 52);
  return p * sc;
}

// ---------------- K0a: vw = mean(sparse_W_V, axis=2), ow = mean(sparse_W_O, axis=1) (fp64) ----------
__global__ void k_prep_means(const float* __restrict__ sWV, const float* __restrict__ sWO,
                             double* __restrict__ vw, double* __restrict__ ow) {
  int t = threadIdx.x;
  for (int o = t; o < NHD * HDD; o += 256) {
    const float* p = sWV + (size_t)o * TOPK;
    double s = 0.0;
    for (int i = 0; i < TOPK; i++) s += (double)p[i];
    vw[o] = s * (1.0 / 128.0);
    int h = o >> 6, d = o & 63;
    const float* q = sWO + ((size_t)h * TOPK) * HDD + d;
    double s2 = 0.0;
    for (int i = 0; i < TOPK; i++) s2 += (double)q[(size_t)i * HDD];
    ow[o] = s2 * (1.0 / 128.0);
  }
}

// ---------------- K0b: WVP[(n*16+h), j] = sum_d W_V[n*64+d, j]*vw[h,d]  (fp64)
//                       G[(m*16+h), o]  = sum_d ow[h,d]*W_O[o, m*64+d]  (fp32) ----------------------
__global__ void k_prep_wvp_g(const float* __restrict__ W_V, const float* __restrict__ W_O,
                             const double* __restrict__ vw, const double* __restrict__ ow,
                             double* __restrict__ WVP, float* __restrict__ G) {
  int blk = blockIdx.x;
  int t = threadIdx.x;
  if (blk < 256) {
    int n = blk >> 4, h = blk & 15;
    for (int j = t; j < HID; j += 256) {
      double s = 0.0;
      for (int d = 0; d < 64; d++)
        s += (double)W_V[(size_t)(n * 64 + d) * HID + j] * vw[h * 64 + d];
      WVP[(size_t)blk * HID + j] = s;
    }
  } else {
    int r = blk - 256;
    int m = r >> 4, h = r & 15;
    for (int o = t; o < HID; o += 256) {
      double s = 0.0;
      for (int d = 0; d < 64; d++)
        s += ow[h * 64 + d] * (double)W_O[(size_t)o * HID + m * 64 + d];
      G[(size_t)r * HID + o] = (float)s;
    }
  }
}

// ---------------- K1: Q/K projection (fp64 accumulate) + per-head LayerNorm, store fp64 -------------
// Paired-plane fp64 LDS + (256,4) pin (r15-verified best).
__global__ __launch_bounds__(256, 4) void k_proj_qk(
    const float* __restrict__ x, const float* __restrict__ W_Q, const float* __restrict__ W_K,
    const float* __restrict__ qw, const float* __restrict__ qb,
    const float* __restrict__ kw, const float* __restrict__ kb,
    double* __restrict__ Qh, double* __restrict__ Kh) {
  __shared__ double smem[4352];   // planes A0|A1|B0|B1, each [32][34]; Cs[64][65] overlays
  __shared__ double red[64][4];
  double (*Cs)[65] = (double(*)[65])smem;

  int rt = blockIdx.x, ot = blockIdx.y;
  bool isQ = (ot < 16);
  const float* W = isQ ? W_Q : W_K;
  int head = isQ ? ot : ot - 16;
  int o0 = head * 64;
  int t = threadIdx.x;
  int tr = t >> 4, tc = t & 15;

  double acc[4][4];
  #pragma unroll
  for (int i = 0; i < 4; i++)
    #pragma unroll
    for (int j = 0; j < 4; j++) acc[i][j] = 0.0;

  for (int k0 = 0; k0 < HID; k0 += 32) {
    #pragma unroll
    for (int i = 0; i < 8; i++) {
      int idx = t + i * 256;
      int r = idx >> 5, c = idx & 31;
      int plane = (r >> 1) & 1;
      int slot  = ((r >> 2) << 1) | (r & 1);
      smem[plane * 1088 + c * 34 + slot]        = (double)x[(size_t)(rt * 64 + r) * HID + k0 + c];
      smem[2176 + plane * 1088 + c * 34 + slot] = (double)W[(size_t)(o0 + r) * HID + k0 + c];
    }
    __syncthreads();
    #pragma unroll 1
    for (int kk = 0; kk < 32; kk++) {
      double2 a01 = *(const double2*)&smem[kk * 34 + 2 * tr];
      double2 a23 = *(const double2*)&smem[1088 + kk * 34 + 2 * tr];
      double2 b01 = *(const double2*)&smem[2176 + kk * 34 + 2 * tc];
      double2 b23 = *(const double2*)&smem[3264 + kk * 34 + 2 * tc];
      double a[4], b[4];
      a[0] = a01.x; a[1] = a01.y; a[2] = a23.x; a[3] = a23.y;
      b[0] = b01.x; b[1] = b01.y; b[2] = b23.x; b[3] = b23.y;
      #pragma unroll
      for (int i = 0; i < 4; i++)
        #pragma unroll
        for (int j = 0; j < 4; j++) acc[i][j] = fma(a[i], b[j], acc[i][j]);
    }
    __syncthreads();
  }

  #pragma unroll
  for (int i = 0; i < 4; i++)
    #pragma unroll
    for (int j = 0; j < 4; j++) Cs[tr * 4 + i][tc * 4 + j] = acc[i][j];
  __syncthreads();

  // LayerNorm per row (64 values), fp64, two-pass like the reference
  int r = t >> 2, p = t & 3;
  double s = 0.0;
  for (int i = 0; i < 16; i++) s += Cs[r][p * 16 + i];
  red[r][p] = s;
  __syncthreads();
  double mu = (red[r][0] + red[r][1] + red[r][2] + red[r][3]) * (1.0 / 64.0);
  __syncthreads();
  double s2 = 0.0;
  for (int i = 0; i < 16; i++) { double dl = Cs[r][p * 16 + i] - mu; s2 += dl * dl; }
  red[r][p] = s2;
  __syncthreads();
  double var = (red[r][0] + red[r][1] + red[r][2] + red[r][3]) * (1.0 / 64.0);
  double inv = 1.0 / sqrt(var + 1e-5);

  int R = rt * 64 + r;
  int b = R >> 11, ss = R & 2047;
  const float* lw = isQ ? qw : kw;
  const float* lb = isQ ? qb : kb;
  double* outp = isQ ? Qh : Kh;
  size_t base = (((size_t)b * 16 + head) * SEQ + ss) * 64;
  for (int i = 0; i < 16; i++) {
    int d = p * 16 + i;
    outp[base + d] = (Cs[r][d] - mu) * inv * (double)lw[d] + (double)lb[d];
  }
}

// ---------------- K1b: Vp = x @ WVP^T (fp64 acc, fp64 store), layout [b][n][k][h] -------------------
__global__ __launch_bounds__(256) void k_proj_vp(
    const float* __restrict__ x, const double* __restrict__ WVP, double* __restrict__ Vp) {
  __shared__ double smem[4352];
  int rt = blockIdx.x, ot = blockIdx.y;
  int t = threadIdx.x, tr = t >> 4, tc = t & 15;

  double acc[4][4];
  #pragma unroll
  for (int i = 0; i < 4; i++)
    #pragma unroll
    for (int j = 0; j < 4; j++) acc[i][j] = 0.0;

  for (int k0 = 0; k0 < HID; k0 += 32) {
    #pragma unroll
    for (int i = 0; i < 8; i++) {
      int idx = t + i * 256;
      int r = idx >> 5, c = idx & 31;
      int plane = (r >> 1) & 1;
      int slot  = ((r >> 2) << 1) | (r & 1);
      smem[plane * 1088 + c * 34 + slot]        = (double)x[(size_t)(rt * 64 + r) * HID + k0 + c];
      smem[2176 + plane * 1088 + c * 34 + slot] = WVP[(size_t)(ot * 64 + r) * HID + k0 + c];
    }
    __syncthreads();
    #pragma unroll 1
    for (int kk = 0; kk < 32; kk++) {
      double2 a01 = *(const double2*)&smem[kk * 34 + 2 * tr];
      double2 a23 = *(const double2*)&smem[1088 + kk * 34 + 2 * tr];
      double2 b01 = *(const double2*)&smem[2176 + kk * 34 + 2 * tc];
      double2 b23 = *(const double2*)&smem[3264 + kk * 34 + 2 * tc];
      double a[4], b[4];
      a[0] = a01.x; a[1] = a01.y; a[2] = a23.x; a[3] = a23.y;
      b[0] = b01.x; b[1] = b01.y; b[2] = b23.x; b[3] = b23.y;
      #pragma unroll
      for (int i = 0; i < 4; i++)
        #pragma unroll
        for (int j = 0; j < 4; j++) acc[i][j] = fma(a[i], b[j], acc[i][j]);
    }
    __syncthreads();
  }
  #pragma unroll
  for (int i = 0; i < 4; i++) {
    int R = rt * 64 + tr * 4 + i;
    int b = R >> 11, k = R & 2047;
    #pragma unroll
    for (int j = 0; j < 4; j++) {
      int cc = ot * 64 + tc * 4 + j;
      int n = cc >> 4, h = cc & 15;
      Vp[((((size_t)b * 16 + n) * SEQ) + k) * 16 + h] = acc[i][j];
    }
  }
}

// ---------------- K2: attention, no-max softmax accumulation in fp64 --------------------------------
// r6/r12/r14 LDS-staged body. r17 measured unroll 2 = -36us (dependency-window diagnosis confirmed);
// this round widens the window one step: unroll 4. Values and per-accumulator FMA order unchanged.
__global__ __launch_bounds__(256, 2) void k_attn(
    const double* __restrict__ Qh, const double* __restrict__ Kh,
    const double* __restrict__ Vp, double* __restrict__ pnum, double* __restrict__ pden) {
  int kh = blockIdx.x;  // key split index
  int qt = blockIdx.y;  // query tile
  int bn = blockIdx.z;  // (b*16+n)
  int t = threadIdx.x;
  int s = qt * 256 + t;
  int kspan = SEQ / gridDim.x;

  __shared__ double2 K2[64][32];   // [key][d/2]
  __shared__ double2 V2[64][8];    // [key][h/2]

  double2 q2[32];
  const double2* qp = (const double2*)(Qh + ((size_t)bn * SEQ + s) * 64);
  #pragma unroll
  for (int d = 0; d < 32; d++) q2[d] = qp[d];

  double2 num2[8];
  #pragma unroll
  for (int i = 0; i < 8; i++) { num2[i].x = 0.0; num2[i].y = 0.0; }
  double den = 0.0;

  int k0 = kh * kspan;
  for (int kc = 0; kc < kspan; kc += 64) {
    const double2* kb = (const double2*)(Kh + ((size_t)bn * SEQ + k0 + kc) * 64);
    #pragma unroll
    for (int i = 0; i < 8; i++) {
      int idx = t + i * 256;             // 2048 double2
      K2[idx >> 5][idx & 31] = kb[idx];
    }
    const double2* vb = (const double2*)(Vp + ((size_t)bn * SEQ + k0 + kc) * 16);
    #pragma unroll
    for (int i = 0; i < 2; i++) {
      int idx = t + i * 256;             // 512 double2
      V2[idx >> 3][idx & 7] = vb[idx];
    }
    __syncthreads();
    #pragma unroll 4
    for (int kk = 0; kk < 64; kk += 4) {
      double s0 = 0.0, s1 = 0.0, s2 = 0.0, s3 = 0.0;
      #pragma unroll
      for (int d2 = 0; d2 < 32; d2++) {
        double2 qq = q2[d2];
        double2 k0v = K2[kk + 0][d2];
        double2 k1v = K2[kk + 1][d2];
        double2 k2v = K2[kk + 2][d2];
        double2 k3v = K2[kk + 3][d2];
        s0 = fma(qq.x, k0v.x, s0); s0 = fma(qq.y, k0v.y, s0);
        s1 = fma(qq.x, k1v.x, s1); s1 = fma(qq.y, k1v.y, s1);
        s2 = fma(qq.x, k2v.x, s2); s2 = fma(qq.y, k2v.y, s2);
        s3 = fma(qq.x, k3v.x, s3); s3 = fma(qq.y, k3v.y, s3);
      }
      double e0 = fast_exp(s0 * 0.125);
      double e1 = fast_exp(s1 * 0.125);
      double e2 = fast_exp(s2 * 0.125);
      double e3 = fast_exp(s3 * 0.125);
      den += (e0 + e1) + (e2 + e3);
      #pragma unroll
      for (int h2 = 0; h2 < 8; h2++) {
        double2 v0 = V2[kk + 0][h2];
        double2 v1 = V2[kk + 1][h2];
        double2 v2 = V2[kk + 2][h2];
        double2 v3 = V2[kk + 3][h2];
        double2 a = num2[h2];
        a.x = fma(e0, v0.x, a.x); a.x = fma(e1, v1.x, a.x);
        a.x = fma(e2, v2.x, a.x); a.x = fma(e3, v3.x, a.x);
        a.y = fma(e0, v0.y, a.y); a.y = fma(e1, v1.y, a.y);
        a.y = fma(e2, v2.y, a.y); a.y = fma(e3, v3.y, a.y);
        num2[h2] = a;
      }
    }
    __syncthreads();
  }
  size_t pb = ((size_t)kh * 32 + bn) * SEQ + s;
  pden[pb] = den;
  #pragma unroll
  for (int h2 = 0; h2 < 8; h2++) {
    pnum[pb * 16 + 2 * h2]     = num2[h2].x;
    pnum[pb * 16 + 2 * h2 + 1] = num2[h2].y;
  }
}

// ---------------- K2b: combine key splits, divide, scatter into z-row layout (fp64) -----------------
__global__ void k_combine(const double* __restrict__ pnum, const double* __restrict__ pden,
                          double* __restrict__ zrow, int nkh) {
  int id = blockIdx.x * 256 + threadIdx.x;  // bn*2048 + s, 65536 total
  int bn = id >> 11, s = id & 2047;
  int b = bn >> 4, n = bn & 15;
  double den = 0.0;
  for (int j = 0; j < nkh; j++) den += pden[(size_t)j * 65536 + id];
  int bp = b * 16 + (s >> 7);          // mixed "batch" index of context_flat
  int np = ((s & 127) << 4) | n;       // mixed candidate index
  for (int h = 0; h < 16; h++) {
    double nm = 0.0;
    for (int j = 0; j < nkh; j++) nm += pnum[((size_t)j * 65536 + id) * 16 + h];
    zrow[((size_t)bp * 16 + h) * 2048 + np] = nm / den;
  }
}

// ---------------- K3: exact top-128 per row via radix binary search on monotone uint64 keys ---------
__device__ inline unsigned long long dkey(double v) {
  unsigned long long u = (unsigned long long)__double_as_longlong(v);
  return (u & 0x8000000000000000ULL) ? ~u : (u | 0x8000000000000000ULL);
}

__global__ __launch_bounds__(256) void k_topk(const double* __restrict__ zrow,
                                              float* __restrict__ zs) {
  int row = blockIdx.x;  // (bp*16+h) in [0,512)
  int t = threadIdx.x;
  const double* src = zrow + (size_t)row * 2048;
  double v[8];
  unsigned long long key[8];
  #pragma unroll
  for (int i = 0; i < 8; i++) { v[i] = src[t + i * 256]; key[i] = dkey(v[i]); }

  __shared__ unsigned sh_cnt[4];
  __shared__ unsigned sh_cg[4], sh_ce[4];
  int w = t >> 6, lane = t & 63;

  unsigned long long lo = 0ULL, hi = 0xFFFFFFFFFFFFFFFFULL;
  while (lo < hi) {
    unsigned long long mid = lo + ((hi - lo) >> 1);
    unsigned c = 0;
    #pragma unroll
    for (int i = 0; i < 8; i++) c += (key[i] > mid) ? 1u : 0u;
    for (int off = 32; off; off >>= 1) c += __shfl_down(c, off);
    if (lane == 0) sh_cnt[w] = c;
    __syncthreads();
    unsigned total = sh_cnt[0] + sh_cnt[1] + sh_cnt[2] + sh_cnt[3];
    __syncthreads();
    if (total < TOPK) hi = mid; else lo = mid + 1;
  }
  unsigned long long tau = lo;

  unsigned cg = 0, ce = 0;
  #pragma unroll
  for (int i = 0; i < 8; i++) {
    cg += (key[i] > tau) ? 1u : 0u;
    ce += (key[i] == tau) ? 1u : 0u;
  }
  for (int off = 32; off; off >>= 1) { cg += __shfl_down(cg, off); ce += __shfl_down(ce, off); }
  if (lane == 0) { sh_cg[w] = cg; sh_ce[w] = ce; }
  __syncthreads();
  unsigned c_gt = sh_cg[0] + sh_cg[1] + sh_cg[2] + sh_cg[3];
  unsigned c_eq = sh_ce[0] + sh_ce[1] + sh_ce[2] + sh_ce[3];
  unsigned need = TOPK - c_gt;

  unsigned idxThr = 2048;
  if (c_eq > need) {
    unsigned l2 = 0, h2 = 2048;
    while (l2 < h2) {
      unsigned m2 = (l2 + h2) >> 1;
      unsigned c = 0;
      #pragma unroll
      for (int i = 0; i < 8; i++) {
        unsigned idx = (unsigned)(t + i * 256);
        c += (key[i] == tau && idx < m2) ? 1u : 0u;
      }
      for (int off = 32; off; off >>= 1) c += __shfl_down(c, off);
      if (lane == 0) sh_cnt[w] = c;
      __syncthreads();
      unsigned tot = sh_cnt[0] + sh_cnt[1] + sh_cnt[2] + sh_cnt[3];
      __syncthreads();
      if (tot >= need) h2 = m2; else l2 = m2 + 1;
    }
    idxThr = l2;
  }

  float* dst = zs + (size_t)row * 2048;
  #pragma unroll
  for (int i = 0; i < 8; i++) {
    unsigned idx = (unsigned)(t + i * 256);
    bool keep = (key[i] > tau) ||
                (key[i] == tau && (c_eq <= need || idx < idxThr));
    dst[idx] = keep ? (float)v[i] : 0.0f;
  }
}

// ---------------- K4: out = Z2 @ G  (4096 x 256 x 1024, fp32) ---------------------------------------
__global__ __launch_bounds__(256) void k_out(const float* __restrict__ zs,
                                             const float* __restrict__ G,
                                             float* __restrict__ out) {
  __shared__ float Al[64][65];
  __shared__ float Bl[64][65];
  int rt = blockIdx.x, ot = blockIdx.y;
  int t = threadIdx.x, tr = t >> 4, tc = t & 15;
  int Rb = rt * 64;
  int b = Rb >> 11, s0 = Rb & 2047;

  float acc[4][4];
  #pragma unroll
  for (int i = 0; i < 4; i++)
    #pragma unroll
    for (int j = 0; j < 4; j++) acc[i][j] = 0.0f;

  for (int kc = 0; kc < 256; kc += 64) {
    #pragma unroll
    for (int i = 0; i < 16; i++) {
      int idx = t + i * 256;
      int c = idx >> 6, r = idx & 63;
      int cc = kc + c;
      Al[r][c] = zs[(((size_t)(b * 16 + (cc >> 4))) * 16 + (cc & 15)) * 2048 + s0 + r];
      Bl[c][r] = G[(size_t)(kc + c) * HID + ot * 64 + r];
    }
    __syncthreads();
    #pragma unroll 1
    for (int kk = 0; kk < 64; kk++) {
      float a[4], bb[4];
      #pragma unroll
      for (int i = 0; i < 4; i++) a[i] = Al[tr * 4 + i][kk];
      #pragma unroll
      for (int j = 0; j < 4; j++) bb[j] = Bl[kk][tc * 4 + j];
      #pragma unroll
      for (int i = 0; i < 4; i++)
        #pragma unroll
        for (int j = 0; j < 4; j++) acc[i][j] = fmaf(a[i], bb[j], acc[i][j]);
    }
    __syncthreads();
  }
  #pragma unroll
  for (int i = 0; i < 4; i++) {
    int R = Rb + tr * 4 + i;
    #pragma unroll
    for (int j = 0; j < 4; j++)
      out[(size_t)R * HID + ot * 64 + tc * 4 + j] = acc[i][j];
  }
}

// ---------------- launch ----------------------------------------------------------------------------
extern "C" void kernel_launch(void* const* d_in, const int* in_sizes, int n_in,
                              void* d_out, int out_size, void* d_ws, size_t ws_size,
                              hipStream_t stream) {
  const float* x   = (const float*)d_in[0];
  const float* W_Q = (const float*)d_in[1];
  const float* W_K = (const float*)d_in[2];
  const float* W_V = (const float*)d_in[3];
  const float* W_O = (const float*)d_in[4];
  const float* qw  = (const float*)d_in[5];
  const float* qb  = (const float*)d_in[6];
  const float* kw  = (const float*)d_in[7];
  const float* kb  = (const float*)d_in[8];
  const float* sWV = (const float*)d_in[9];
  const float* sWO = (const float*)d_in[10];
  float* out = (float*)d_out;
  char* ws = (char*)d_ws;

  // 4-way key split (r6-verified to fit); fall back to 2-way if workspace is smaller.
  const size_t NEED4 = 114311168ULL;
  int nkh = (ws_size >= NEED4) ? 4 : 2;

  double* Qh   = (double*)(ws + 0);          // 33,554,432
  double* Kh   = (double*)(ws + 33554432ULL);// 33,554,432
  double* Vp   = (double*)(ws + 67108864ULL);// 8,388,608
  double* WVP  = (double*)(ws + 75497472ULL);// 2,097,152
  float*  G    = (float*) (ws + 77594624ULL);// 1,048,576
  double* vw   = (double*)(ws + 78643200ULL);// 8,192
  double* ow   = (double*)(ws + 78651392ULL);// 8,192
  double* pnum = (double*)(ws + 78659584ULL);// nkh * 8,388,608
  double* pden = (double*)(ws + 78659584ULL + (size_t)nkh * 8388608ULL); // nkh * 524,288
  double* zrow = (double*)(ws + 0);          // overlay: 8,388,608
  float*  zs   = (float*) (ws + 8388608ULL); // overlay: 4,194,304

  k_prep_means<<<dim3(1), dim3(256), 0, stream>>>(sWV, sWO, vw, ow);
  k_prep_wvp_g<<<dim3(512), dim3(256), 0, stream>>>(W_V, W_O, vw, ow, WVP, G);
  k_proj_qk<<<dim3(64, 32), dim3(256), 0, stream>>>(x, W_Q, W_K, qw, qb, kw, kb, Qh, Kh);
  k_proj_vp<<<dim3(64, 4), dim3(256), 0, stream>>>(x, WVP, Vp);
  k_attn<<<dim3(nkh, 8, 32), dim3(256), 0, stream>>>(Qh, Kh, Vp, pnum, pden);
  k_combine<<<dim3(256), dim3(256), 0, stream>>>(pnum, pden, zrow, nkh);
  k_topk<<<dim3(512), dim3(256), 0, stream>>>(zrow, zs);
  k_out<<<dim3(64, 16), dim3(256), 0, stream>>>(zs, G, out);
}